// Round 7
// baseline (444.942 us; speedup 1.0000x reference)
//
#include <hip/hip_runtime.h>
#include <cstdint>
#include <cstddef>

// SummaryAdapter fused kernel for MI355X (gfx950), v7: per-wave private DMA
// streams, ZERO barriers. Each wave owns one 16-row s-tile; h is streamed via
// global_load_lds gathers into a wave-private 2x4KB LDS double buffer laid
// out 16B-column-major (conflict-free ds_read_b128). Counted vmcnt(4) keeps
// the next chunk's DMA in flight across each chunk's compute.
// L=8 B=2 S=4096 D=2048 N=128 Ds=1024 Da=64.
//
// Workspace layout (bytes):          off      size
//   KF  frag bf16                      0    262144
//   VF  frag bf16                 262144    262144
//   WqF frag bf16                 524288   2097152
//   WoF frag bf16                2621440   2097152
// Requires ws_size >= 4718592.

typedef __attribute__((ext_vector_type(8))) short short8;   // 8 x bf16
typedef __attribute__((ext_vector_type(4))) float f32x4;

#define MFMA16(a, b, c) __builtin_amdgcn_mfma_f32_16x16x32_bf16((a), (b), (c), 0, 0, 0)
#define WAITV4 asm volatile("s_waitcnt vmcnt(4)" ::: "memory")
#define WAITV0 asm volatile("s_waitcnt vmcnt(0)" ::: "memory")
#define CFENCE asm volatile("" ::: "memory")

__device__ __forceinline__ unsigned short f2bf(float f) {
  unsigned int x = __builtin_bit_cast(unsigned int, f);
  x += 0x7fffu + ((x >> 16) & 1u);        // RNE
  return (unsigned short)(x >> 16);
}
__device__ __forceinline__ short8 cvt8v(f32x4 a, f32x4 b) {
  short8 r;
  r[0] = (short)f2bf(a[0]); r[1] = (short)f2bf(a[1]);
  r[2] = (short)f2bf(a[2]); r[3] = (short)f2bf(a[3]);
  r[4] = (short)f2bf(b[0]); r[5] = (short)f2bf(b[1]);
  r[6] = (short)f2bf(b[2]); r[7] = (short)f2bf(b[3]);
  return r;
}
__device__ __forceinline__ short8 ld_cvt8(const float* p) {
  f32x4 v0 = *(const f32x4*)p, v1 = *(const f32x4*)(p + 4);
  return cvt8v(v0, v1);
}
// async 16B/lane global->LDS DMA; lds base wave-uniform, global per-lane
__device__ __forceinline__ void gload_lds16(const void* g, void* l) {
  typedef __attribute__((address_space(1))) const unsigned int gu32;
  typedef __attribute__((address_space(3))) unsigned int lu32;
  __builtin_amdgcn_global_load_lds((gu32*)(const unsigned int*)g,
                                   (lu32*)(unsigned int*)l, 16, 0, 0);
}

// ---------------- pre 1: K = bank@Wk^T, V = bank@Wv^T via MFMA -------------
__global__ __launch_bounds__(64)
void pre_kv_kernel(const float* __restrict__ bank,
                   const float* __restrict__ Wk,
                   const float* __restrict__ Wv,
                   unsigned short* __restrict__ KF, unsigned short* __restrict__ VF) {
  int bid = blockIdx.x;
  int at = bid & 3, nt = (bid >> 2) & 7, kv = (bid >> 5) & 1;
  int b = (bid >> 6) & 1, l = bid >> 7;
  int lane = threadIdx.x & 63;
  int lo = lane & 15, hi = lane >> 4;
  const float* W  = (kv ? Wv : Wk) + (size_t)l * 65536;
  const float* bk = bank + (size_t)b * 131072;
  int lbq = l * 2 + b;
  f32x4 acc = (f32x4){0.f, 0.f, 0.f, 0.f};
  for (int ks = 0; ks < 32; ++ks) {
    short8 A = ld_cvt8(bk + (nt * 16 + lo) * 1024 + ks * 32 + hi * 8);
    short8 B = ld_cvt8(W + (at * 16 + lo) * 1024 + ks * 32 + hi * 8);
    acc = MFMA16(A, B, acc);
  }
  for (int r = 0; r < 4; ++r) {
    int n = nt * 16 + hi * 4 + r;
    int a = at * 16 + lo;
    unsigned short v = f2bf(acc[r]);
    if (kv == 0) {
      int idx = ((lbq * 8 + (n >> 4)) * 2 + (a >> 5)) * 512 +
                (((a >> 3) & 3) * 16 + (n & 15)) * 8 + (a & 7);
      KF[idx] = v;
    } else {
      int idx = ((lbq * 4 + (a >> 4)) * 4 + (n >> 5)) * 512 +
                (((n >> 3) & 3) * 16 + (a & 15)) * 8 + (n & 7);
      VF[idx] = v;
    }
  }
}

// ---------------- pre 2: Wq/Wo -> bf16 fragment layout ---------------------
__global__ void pre_frag_kernel(const float* __restrict__ Wq, const float* __restrict__ Wo,
                                unsigned short* __restrict__ WqF, unsigned short* __restrict__ WoF) {
  int idx = blockIdx.x * 256 + threadIdx.x;        // 262144 threads
  if (idx < 131072) {
    int t = idx;
    int lane = t & 63, ks = (t >> 6) & 63, at = (t >> 12) & 3, l = t >> 14;
    int a = at * 16 + (lane & 15), d = ks * 32 + (lane >> 4) * 8;
    *(short8*)(WqF + (size_t)t * 8) = ld_cvt8(Wq + ((size_t)(l * 64 + a)) * 2048 + d);
  } else {
    int t = idx - 131072;
    int lane = t & 63, ks = (t >> 6) & 1, dt = (t >> 7) & 127, l = t >> 14;
    int d = dt * 16 + (lane & 15), a = ks * 32 + (lane >> 4) * 8;
    *(short8*)(WoF + (size_t)t * 8) = ld_cvt8(Wo + ((size_t)(l * 2048 + d)) * 64 + a);
  }
}

// ---------------- main fused kernel ----------------------------------------
// 1024 blocks x 256 threads; tile-per-WAVE, all 4096 tiles co-resident
// (16 waves/CU). No __syncthreads / s_barrier anywhere.
// Per-wave LDS: stage[2][4096] chunks, reused as scratch after P1.
// Chunk = 16 rows x 64 f32, stored 16B-column-major: LDS off = c4*256+r*16
// (c4 = 16B col slot 0..15, r = row). A-read banks: lo*4 mod 32 -> 2-way.
__global__ __launch_bounds__(256, 4)
void adapter_main(const float* __restrict__ hidden,
                  const unsigned short* __restrict__ KF, const unsigned short* __restrict__ VF,
                  const unsigned short* __restrict__ WqF, const unsigned short* __restrict__ WoF,
                  const float* __restrict__ gates, float* __restrict__ out) {
  __shared__ __align__(1024) char stage[4][8192];

  // XCD-bijective swizzle (1024 % 8 == 0): XCD x gets exactly layer x ->
  // that XCD's L2 holds only its layer's WqF/WoF/KF/VF.
  int bid0 = blockIdx.x;
  int bid = (bid0 & 7) * 128 + (bid0 >> 3);
  int wave = threadIdx.x >> 6, lane = threadIdx.x & 63;
  int lo = lane & 15, hi = lane >> 4;
  int t = bid * 4 + wave;                          // tile id 0..4095
  int st = t & 255, b = (t >> 8) & 1, l = t >> 9;
  size_t hbase = ((size_t)(l * 2 + b) * 4096 + st * 16) * 2048;
  const float* hsrc = hidden + hbase;
  const char* hby = (const char*)hsrc;
  float gate = 1.0f / (1.0f + __expf(-gates[l]));
  int lb = l * 2 + b;
  char* stg = stage[wave];
  float* qs = (float*)stg;                         // P1-done -> scratch
  unsigned short* qsu = (unsigned short*)stg;

  // per-lane DMA gather source: row = lane&15, 16B col slot = lane>>4
  size_t dsrc = (size_t)(lane & 15) * 8192 + (size_t)(lane >> 4) * 16;

#define DMA_CHUNK(c, buf)                                                   \
  do {                                                                      \
    const char* s_ = hby + (size_t)(c) * 256 + dsrc;                        \
    char* d_ = stg + (buf) * 4096;                                          \
    gload_lds16(s_, d_);                                                    \
    gload_lds16(s_ + 64, d_ + 1024);                                        \
    gload_lds16(s_ + 128, d_ + 2048);                                       \
    gload_lds16(s_ + 192, d_ + 3072);                                       \
  } while (0)

  // ---- Phase 1: Q = h @ Wq^T, 32 chunks of 16x64 f32, zero barriers ----
  f32x4 qacc[4];
  #pragma unroll
  for (int at = 0; at < 4; ++at) qacc[at] = (f32x4){0.f, 0.f, 0.f, 0.f};
  {
    const unsigned short* wqb = WqF + ((size_t)l * 256) * 512 + lane * 8;
    DMA_CHUNK(0, 0);
    CFENCE;
    #pragma unroll 1
    for (int c = 0; c < 32; ++c) {
      short8 Bf[4][2];                             // B-frags for ks=2c,2c+1
      #pragma unroll
      for (int at = 0; at < 4; ++at)
        #pragma unroll
        for (int s = 0; s < 2; ++s)
          Bf[at][s] = *(const short8*)(wqb + ((size_t)at * 64 + 2 * c + s) * 512);
      CFENCE;
      if (c < 31) {
        if (c & 1) DMA_CHUNK(c + 1, 0); else DMA_CHUNK(c + 1, 1);
        CFENCE;
        WAITV4;                                    // B(c)+DMA(c) done; DMA(c+1) flying
      } else {
        WAITV0;
      }
      const char* sb = stg + (c & 1) * 4096 + lo * 16;
      #pragma unroll
      for (int s = 0; s < 2; ++s) {
        f32x4 v0 = *(const f32x4*)(sb + (s * 8 + hi * 2) * 256);
        f32x4 v1 = *(const f32x4*)(sb + (s * 8 + hi * 2 + 1) * 256);
        short8 A = cvt8v(v0, v1);
        #pragma unroll
        for (int at = 0; at < 4; ++at)
          qacc[at] = MFMA16(A, Bf[at][s], qacc[at]);
      }
    }
  }
#undef DMA_CHUNK

  // ---- write Q (scaled) to per-wave scratch (stage now free) ----
  #pragma unroll
  for (int at = 0; at < 4; ++at)
    #pragma unroll
    for (int r = 0; r < 4; ++r)                    // fold 1/sqrt(64)
      qs[(hi * 4 + r) * 68 + at * 16 + lo] = qacc[at][r] * 0.125f;

  // ---- Phase 2: scores = Q @ K^T, all 8 n-tiles in registers ----
  f32x4 sacc[8];
  {
    short8 afrag[2];
    #pragma unroll
    for (int ks = 0; ks < 2; ++ks) {
      const float* qp = qs + lo * 68 + ks * 32 + hi * 8;
      afrag[ks] = cvt8v(*(const f32x4*)qp, *(const f32x4*)(qp + 4));
    }
    const unsigned short* kf = KF + ((size_t)lb * 16) * 512 + lane * 8;
    short8 kfr[8][2];
    #pragma unroll
    for (int nt = 0; nt < 8; ++nt) {
      kfr[nt][0] = *(const short8*)(kf + (size_t)nt * 1024);
      kfr[nt][1] = *(const short8*)(kf + (size_t)nt * 1024 + 512);
    }
    #pragma unroll
    for (int nt = 0; nt < 8; ++nt) {
      f32x4 a0 = (f32x4){0.f, 0.f, 0.f, 0.f};
      a0 = MFMA16(afrag[0], kfr[nt][0], a0);
      sacc[nt] = MFMA16(afrag[1], kfr[nt][1], a0);
    }
  }

  // ---- Phase 3: in-register softmax (row = hi*4+r, cols over lo) ----
  {
    #pragma unroll
    for (int r = 0; r < 4; ++r) {
      float m = sacc[0][r];
      #pragma unroll
      for (int nt = 1; nt < 8; ++nt) m = fmaxf(m, sacc[nt][r]);
      m = fmaxf(m, __shfl_xor(m, 1)); m = fmaxf(m, __shfl_xor(m, 2));
      m = fmaxf(m, __shfl_xor(m, 4)); m = fmaxf(m, __shfl_xor(m, 8));
      float s = 0.f;
      #pragma unroll
      for (int nt = 0; nt < 8; ++nt) {
        float e = __expf(sacc[nt][r] - m);
        sacc[nt][r] = e; s += e;
      }
      s += __shfl_xor(s, 1); s += __shfl_xor(s, 2);
      s += __shfl_xor(s, 4); s += __shfl_xor(s, 8);
      float inv = 1.0f / s;
      #pragma unroll
      for (int nt = 0; nt < 8; ++nt) sacc[nt][r] *= inv;
    }
    #pragma unroll
    for (int nt = 0; nt < 8; ++nt)                 // P bf16 [16][136], 272 B/row
      #pragma unroll
      for (int r = 0; r < 4; ++r)
        qsu[(hi * 4 + r) * 136 + nt * 16 + lo] = f2bf(sacc[nt][r]);
  }

  // ---- Phase 4: attn_out = P @ V ----
  {
    short8 pfrag[4];
    #pragma unroll
    for (int ks = 0; ks < 4; ++ks)
      pfrag[ks] = *(const short8*)(stg + lo * 272 + ks * 64 + hi * 16);
    const unsigned short* vf = VF + ((size_t)lb * 16) * 512 + lane * 8;
    short8 vfr[16];
    #pragma unroll
    for (int q = 0; q < 16; ++q)
      vfr[q] = *(const short8*)(vf + (size_t)q * 512);
    f32x4 ao[4];
    #pragma unroll
    for (int at = 0; at < 4; ++at) {
      f32x4 a = (f32x4){0.f, 0.f, 0.f, 0.f};
      #pragma unroll
      for (int ks = 0; ks < 4; ++ks)
        a = MFMA16(pfrag[ks], vfr[at * 4 + ks], a);
      ao[at] = a;
    }
    #pragma unroll
    for (int at = 0; at < 4; ++at)
      #pragma unroll
      for (int r = 0; r < 4; ++r)
        qs[(hi * 4 + r) * 68 + at * 16 + lo] = ao[at][r];
  }

  // ---- Phase 5: resid^T = Wo @ attn_out^T; out = hidden + g*resid ----
  {
    short8 bfrag[2];
    #pragma unroll
    for (int ks = 0; ks < 2; ++ks) {
      const float* ap2 = qs + lo * 68 + ks * 32 + hi * 8;
      bfrag[ks] = cvt8v(*(const f32x4*)ap2, *(const f32x4*)(ap2 + 4));
    }
    const unsigned short* wob = WoF + ((size_t)l * 256) * 512 + lane * 8;
    const float* hrow = hsrc + (size_t)lo * 2048 + hi * 4;
    float* orow = out + hbase + (size_t)lo * 2048 + hi * 4;
    #pragma unroll 4
    for (int dt = 0; dt < 128; ++dt) {
      short8 A0 = *(const short8*)(wob + (size_t)dt * 1024);
      short8 A1 = *(const short8*)(wob + (size_t)dt * 1024 + 512);
      f32x4 hv = *(const f32x4*)(hrow + dt * 16);  // L2 hit (fetched in P1)
      f32x4 acc = (f32x4){0.f, 0.f, 0.f, 0.f};
      acc = MFMA16(A0, bfrag[0], acc);
      acc = MFMA16(A1, bfrag[1], acc);
      f32x4 o;
      #pragma unroll
      for (int r = 0; r < 4; ++r) o[r] = hv[r] + gate * acc[r];
      __builtin_nontemporal_store(o, (f32x4*)(orow + dt * 16));
    }
  }
}

extern "C" void kernel_launch(void* const* d_in, const int* in_sizes, int n_in,
                              void* d_out, int out_size, void* d_ws, size_t ws_size,
                              hipStream_t stream) {
  const float* hidden = (const float*)d_in[0];
  const float* bank   = (const float*)d_in[1];
  const float* Wq     = (const float*)d_in[2];
  const float* Wk     = (const float*)d_in[3];
  const float* Wv     = (const float*)d_in[4];
  const float* Wo     = (const float*)d_in[5];
  const float* gates  = (const float*)d_in[6];
  float* out = (float*)d_out;

  char* ws = (char*)d_ws;
  unsigned short* KF  = (unsigned short*)(ws);
  unsigned short* VF  = (unsigned short*)(ws + 262144);
  unsigned short* WqF = (unsigned short*)(ws + 524288);
  unsigned short* WoF = (unsigned short*)(ws + 2621440);

  pre_kv_kernel<<<1024, 64, 0, stream>>>(bank, Wk, Wv, KF, VF);
  pre_frag_kernel<<<1024, 256, 0, stream>>>(Wq, Wo, WqF, WoF);
  adapter_main<<<1024, 256, 0, stream>>>(hidden, KF, VF, WqF, WoF, gates, out);
}

// Round 8
// 307.181 us; speedup vs baseline: 1.4485x; 1.4485x over previous
//
#include <hip/hip_runtime.h>
#include <cstdint>
#include <cstddef>

// SummaryAdapter fused kernel for MI355X (gfx950), v8: block-per-16-row-tile,
// every global h access is a single-row fully-coalesced wave instruction.
// P1: dbuf reg->LDS bf16 staging (XOR swizzle) + Q MFMA.
// P5: per-d-chunk resid MFMA -> padded LDS -> coalesced elementwise add/store.
// 24.8 KB LDS -> 6 blocks/CU; overlap across blocks hides phase serialization.
// L=8 B=2 S=4096 D=2048 N=128 Ds=1024 Da=64.
//
// Workspace layout (bytes):          off      size
//   KF  frag bf16                      0    262144
//   VF  frag bf16                 262144    262144
//   WqF frag bf16                 524288   2097152
//   WoF frag bf16                2621440   2097152
// Requires ws_size >= 4718592.

typedef __attribute__((ext_vector_type(8))) short short8;   // 8 x bf16
typedef __attribute__((ext_vector_type(4))) float f32x4;
typedef __attribute__((ext_vector_type(4))) unsigned short u16x4;

#define MFMA16(a, b, c) __builtin_amdgcn_mfma_f32_16x16x32_bf16((a), (b), (c), 0, 0, 0)

__device__ __forceinline__ unsigned short f2bf(float f) {
  unsigned int x = __builtin_bit_cast(unsigned int, f);
  x += 0x7fffu + ((x >> 16) & 1u);        // RNE
  return (unsigned short)(x >> 16);
}
__device__ __forceinline__ float bf2f(unsigned short u) {
  return __builtin_bit_cast(float, (unsigned int)u << 16);
}
__device__ __forceinline__ short8 cvt8v(f32x4 a, f32x4 b) {
  short8 r;
  r[0] = (short)f2bf(a[0]); r[1] = (short)f2bf(a[1]);
  r[2] = (short)f2bf(a[2]); r[3] = (short)f2bf(a[3]);
  r[4] = (short)f2bf(b[0]); r[5] = (short)f2bf(b[1]);
  r[6] = (short)f2bf(b[2]); r[7] = (short)f2bf(b[3]);
  return r;
}
__device__ __forceinline__ short8 ld_cvt8(const float* p) {
  f32x4 v0 = *(const f32x4*)p, v1 = *(const f32x4*)(p + 4);
  return cvt8v(v0, v1);
}
__device__ __forceinline__ u16x4 pack4(f32x4 v) {
  u16x4 r;
  r[0] = f2bf(v[0]); r[1] = f2bf(v[1]); r[2] = f2bf(v[2]); r[3] = f2bf(v[3]);
  return r;
}

// ---------------- pre 1: K = bank@Wk^T, V = bank@Wv^T via MFMA -------------
__global__ __launch_bounds__(64)
void pre_kv_kernel(const float* __restrict__ bank,
                   const float* __restrict__ Wk,
                   const float* __restrict__ Wv,
                   unsigned short* __restrict__ KF, unsigned short* __restrict__ VF) {
  int bid = blockIdx.x;
  int at = bid & 3, nt = (bid >> 2) & 7, kv = (bid >> 5) & 1;
  int b = (bid >> 6) & 1, l = bid >> 7;
  int lane = threadIdx.x & 63;
  int lo = lane & 15, hi = lane >> 4;
  const float* W  = (kv ? Wv : Wk) + (size_t)l * 65536;
  const float* bk = bank + (size_t)b * 131072;
  int lbq = l * 2 + b;
  f32x4 acc = (f32x4){0.f, 0.f, 0.f, 0.f};
  for (int ks = 0; ks < 32; ++ks) {
    short8 A = ld_cvt8(bk + (nt * 16 + lo) * 1024 + ks * 32 + hi * 8);
    short8 B = ld_cvt8(W + (at * 16 + lo) * 1024 + ks * 32 + hi * 8);
    acc = MFMA16(A, B, acc);
  }
  for (int r = 0; r < 4; ++r) {
    int n = nt * 16 + hi * 4 + r;
    int a = at * 16 + lo;
    unsigned short v = f2bf(acc[r]);
    if (kv == 0) {
      int idx = ((lbq * 8 + (n >> 4)) * 2 + (a >> 5)) * 512 +
                (((a >> 3) & 3) * 16 + (n & 15)) * 8 + (a & 7);
      KF[idx] = v;
    } else {
      int idx = ((lbq * 4 + (a >> 4)) * 4 + (n >> 5)) * 512 +
                (((n >> 3) & 3) * 16 + (a & 15)) * 8 + (n & 7);
      VF[idx] = v;
    }
  }
}

// ---------------- pre 2: Wq/Wo -> bf16 fragment layout ---------------------
__global__ void pre_frag_kernel(const float* __restrict__ Wq, const float* __restrict__ Wo,
                                unsigned short* __restrict__ WqF, unsigned short* __restrict__ WoF) {
  int idx = blockIdx.x * 256 + threadIdx.x;        // 262144 threads
  if (idx < 131072) {
    int t = idx;
    int lane = t & 63, ks = (t >> 6) & 63, at = (t >> 12) & 3, l = t >> 14;
    int a = at * 16 + (lane & 15), d = ks * 32 + (lane >> 4) * 8;
    *(short8*)(WqF + (size_t)t * 8) = ld_cvt8(Wq + ((size_t)(l * 64 + a)) * 2048 + d);
  } else {
    int t = idx - 131072;
    int lane = t & 63, ks = (t >> 6) & 1, dt = (t >> 7) & 127, l = t >> 14;
    int d = dt * 16 + (lane & 15), a = ks * 32 + (lane >> 4) * 8;
    *(short8*)(WoF + (size_t)t * 8) = ld_cvt8(Wo + ((size_t)(l * 2048 + d)) * 64 + a);
  }
}

// ---------------- main fused kernel ----------------------------------------
// 4096 blocks x 256 threads (4 waves), block owns one 16-row s-tile.
// LDS 24832 B static -> 6 blocks/CU:
//   [0,16384)      stage: 2 x [16 rows][512 B bf16], swizzled col^=(row&7)<<4
//                  after P1 reused as: qsc f32[16][68] @0 / P bf16[16][136]
//                  @4352 / ao f32[16][68] @8704
//   [16384,24832)  scb f32[16][132]; reused as resid bf16[16][260] in P5
__global__ __launch_bounds__(256, 6)
void adapter_main(const float* __restrict__ hidden,
                  const unsigned short* __restrict__ KF, const unsigned short* __restrict__ VF,
                  const unsigned short* __restrict__ WqF, const unsigned short* __restrict__ WoF,
                  const float* __restrict__ gates, float* __restrict__ out) {
  __shared__ __align__(16) char smem[24832];
  float* qsc = (float*)smem;                        // [16][68]
  unsigned short* Pb = (unsigned short*)(smem + 4352);  // [16][136]
  float* aob = (float*)(smem + 8704);               // [16][68]
  float* scb = (float*)(smem + 16384);              // [16][132]
  char* resb = smem + 16384;                        // bf16 [16][260]

  // XCD-bijective swizzle (4096 % 8 == 0): XCD x gets 512 tiles = layer x.
  int bid0 = blockIdx.x;
  int bid = (bid0 & 7) * 512 + (bid0 >> 3);
  int st = bid & 255, b = (bid >> 8) & 1, l = bid >> 9;
  int tid = threadIdx.x, wave = tid >> 6, lane = tid & 63;
  int lo = lane & 15, hi = lane >> 4;
  size_t hbase = ((size_t)(l * 2 + b) * 4096 + st * 16) * 2048;
  const char* hby = (const char*)(hidden + hbase);
  float gate = 1.0f / (1.0f + __expf(-gates[l]));
  int lb = l * 2 + b;
  int at = wave;

  // ---- Phase 1: Q = h @ Wq^T; 8 chunks of 16 rows x 1KB, dbuf staging ----
  // Stage load: wave w, sub s2: row = s2*4+w, 64 lanes x 16B contiguous.
  f32x4 sreg[4];
  f32x4 qacc = (f32x4){0.f, 0.f, 0.f, 0.f};
  {
    const unsigned short* wqb = WqF + ((size_t)(l * 4 + at) * 64) * 512 + lane * 8;

#define LOADC(c)                                                             \
    _Pragma("unroll")                                                        \
    for (int s2 = 0; s2 < 4; ++s2) {                                         \
      int row = s2 * 4 + wave;                                               \
      sreg[s2] = *(const f32x4*)(hby + (size_t)row * 8192 + (size_t)(c) * 1024 + lane * 16); \
    }
#define WRITEC(c)                                                            \
    _Pragma("unroll")                                                        \
    for (int s2 = 0; s2 < 4; ++s2) {                                         \
      int row = s2 * 4 + wave;                                               \
      u16x4 pk = pack4(sreg[s2]);                                            \
      *(u16x4*)(smem + ((c) & 1) * 8192 + row * 512 + ((lane * 8) ^ ((row & 7) << 4))) = pk; \
    }

    LOADC(0); WRITEC(0);
    #pragma unroll 1
    for (int c = 0; c < 8; ++c) {
      __syncthreads();                           // chunk c LDS visible
      if (c < 7) LOADC(c + 1);
      const char* rb = smem + (c & 1) * 8192 + lo * 512;
      int sw = (lo & 7) << 4;
      #pragma unroll
      for (int ks = 0; ks < 8; ++ks) {
        short8 A = *(const short8*)(rb + ((ks * 64 + hi * 16) ^ sw));
        short8 B = *(const short8*)(wqb + (size_t)(c * 8 + ks) * 512);
        qacc = MFMA16(A, B, qacc);
      }
      if (c < 7) WRITEC(c + 1);
    }
#undef LOADC
#undef WRITEC
  }

  // ---- write Q (scaled) -> qsc (stage buf0; all waves past chunk-6 reads) ----
  #pragma unroll
  for (int r = 0; r < 4; ++r)                      // fold 1/sqrt(64)
    qsc[(hi * 4 + r) * 68 + at * 16 + lo] = qacc[r] * 0.125f;
  __syncthreads();

  // ---- Phase 2: scores = Q @ K^T -> scb ----
  {
    short8 afrag[2];
    #pragma unroll
    for (int ks = 0; ks < 2; ++ks) {
      const float* qp = qsc + lo * 68 + ks * 32 + hi * 8;
      afrag[ks] = cvt8v(*(const f32x4*)qp, *(const f32x4*)(qp + 4));
    }
    #pragma unroll
    for (int i = 0; i < 2; ++i) {
      int nt = wave * 2 + i;
      f32x4 acc = (f32x4){0.f, 0.f, 0.f, 0.f};
      const unsigned short* kf = KF + ((size_t)(lb * 8 + nt) * 2) * 512 + lane * 8;
      acc = MFMA16(afrag[0], *(const short8*)(kf), acc);
      acc = MFMA16(afrag[1], *(const short8*)(kf + 512), acc);
      #pragma unroll
      for (int r = 0; r < 4; ++r)
        scb[(hi * 4 + r) * 132 + nt * 16 + lo] = acc[r];
    }
  }
  __syncthreads();

  // ---- Phase 3: softmax over N=128 (16 lanes per row) -> Pb bf16 ----
  {
    int row = wave * 4 + hi;
    const float* sp = scb + row * 132 + lo * 8;
    f32x4 v0 = *(const f32x4*)sp, v1 = *(const f32x4*)(sp + 4);
    float m = fmaxf(fmaxf(fmaxf(v0[0], v0[1]), fmaxf(v0[2], v0[3])),
                    fmaxf(fmaxf(v1[0], v1[1]), fmaxf(v1[2], v1[3])));
    m = fmaxf(m, __shfl_xor(m, 1)); m = fmaxf(m, __shfl_xor(m, 2));
    m = fmaxf(m, __shfl_xor(m, 4)); m = fmaxf(m, __shfl_xor(m, 8));
    f32x4 e0, e1; float s = 0.f;
    #pragma unroll
    for (int j = 0; j < 4; ++j) { e0[j] = __expf(v0[j] - m); s += e0[j]; }
    #pragma unroll
    for (int j = 0; j < 4; ++j) { e1[j] = __expf(v1[j] - m); s += e1[j]; }
    s += __shfl_xor(s, 1); s += __shfl_xor(s, 2);
    s += __shfl_xor(s, 4); s += __shfl_xor(s, 8);
    float inv = 1.0f / s;
    #pragma unroll
    for (int j = 0; j < 4; ++j) { e0[j] *= inv; e1[j] *= inv; }
    *(short8*)((char*)Pb + row * 272 + lo * 16) = cvt8v(e0, e1);
  }
  __syncthreads();

  // ---- Phase 4: attn_out = P @ V -> aob ----
  {
    short8 pfrag[4];
    #pragma unroll
    for (int ks = 0; ks < 4; ++ks)
      pfrag[ks] = *(const short8*)((const char*)Pb + lo * 272 + ks * 64 + hi * 16);
    const unsigned short* vf = VF + ((size_t)(lb * 4 + at) * 4) * 512 + lane * 8;
    f32x4 a = (f32x4){0.f, 0.f, 0.f, 0.f};
    #pragma unroll
    for (int ks = 0; ks < 4; ++ks)
      a = MFMA16(pfrag[ks], *(const short8*)(vf + (size_t)ks * 512), a);
    #pragma unroll
    for (int r = 0; r < 4; ++r)
      aob[(hi * 4 + r) * 68 + at * 16 + lo] = a[r];
  }
  __syncthreads();

  // ---- Phase 5: 8 d-chunks of 256 cols: resid MFMA -> LDS -> coalesced add ----
  {
    short8 bfrag[2];
    #pragma unroll
    for (int ks = 0; ks < 2; ++ks) {
      const float* ap2 = aob + lo * 68 + ks * 32 + hi * 8;
      bfrag[ks] = cvt8v(*(const f32x4*)ap2, *(const f32x4*)(ap2 + 4));
    }
    float* ob = out + hbase;
    #pragma unroll 1
    for (int c = 0; c < 8; ++c) {
      #pragma unroll
      for (int j = 0; j < 4; ++j) {
        int dtl = wave * 4 + j;                    // 0..15 within chunk
        int dt = c * 16 + dtl;
        const unsigned short* wo = WoF + ((size_t)(l * 128 + dt) * 2) * 512 + lane * 8;
        short8 A0 = *(const short8*)(wo);
        short8 A1 = *(const short8*)(wo + 512);
        f32x4 acc = (f32x4){0.f, 0.f, 0.f, 0.f};
        acc = MFMA16(A0, bfrag[0], acc);
        acc = MFMA16(A1, bfrag[1], acc);
        // resid^T frag: s = lo, d_local = dtl*16 + hi*4 + r
        *(u16x4*)(resb + lo * 520 + dtl * 32 + hi * 8) = pack4(acc);
      }
      __syncthreads();                             // resid chunk ready
      #pragma unroll
      for (int i2 = 0; i2 < 4; ++i2) {
        int row = i2 * 4 + wave;                   // 1 row per wave-instr
        size_t off = (size_t)row * 8192 + (size_t)c * 1024 + lane * 16;
        f32x4 hv = *(const f32x4*)(hby + off);     // L2/L3 hit (read in P1)
        u16x4 rv = *(const u16x4*)(resb + row * 520 + lane * 8);
        f32x4 o;
        #pragma unroll
        for (int r = 0; r < 4; ++r) o[r] = hv[r] + gate * bf2f(rv[r]);
        __builtin_nontemporal_store(o, (f32x4*)((char*)ob + off));
      }
      __syncthreads();                             // resb reads done
    }
  }
}

extern "C" void kernel_launch(void* const* d_in, const int* in_sizes, int n_in,
                              void* d_out, int out_size, void* d_ws, size_t ws_size,
                              hipStream_t stream) {
  const float* hidden = (const float*)d_in[0];
  const float* bank   = (const float*)d_in[1];
  const float* Wq     = (const float*)d_in[2];
  const float* Wk     = (const float*)d_in[3];
  const float* Wv     = (const float*)d_in[4];
  const float* Wo     = (const float*)d_in[5];
  const float* gates  = (const float*)d_in[6];
  float* out = (float*)d_out;

  char* ws = (char*)d_ws;
  unsigned short* KF  = (unsigned short*)(ws);
  unsigned short* VF  = (unsigned short*)(ws + 262144);
  unsigned short* WqF = (unsigned short*)(ws + 524288);
  unsigned short* WoF = (unsigned short*)(ws + 2621440);

  pre_kv_kernel<<<1024, 64, 0, stream>>>(bank, Wk, Wv, KF, VF);
  pre_frag_kernel<<<1024, 256, 0, stream>>>(Wq, Wo, WqF, WoF);
  adapter_main<<<4096, 256, 0, stream>>>(hidden, KF, VF, WqF, WoF, gates, out);
}